// Round 10
// baseline (503.326 us; speedup 1.0000x reference)
//
#include <hip/hip_runtime.h>
#include <hip/hip_bf16.h>
#include <math.h>

// ---------------- constants ----------------
namespace {
constexpr int Bc   = 2;
constexpr int Nn   = 2048;
constexpr int CACHE= 512;
constexpr int KVL  = 2560;      // CACHE + Nn
constexpr int DM   = 768;
constexpr int NH   = 12;
constexpr int HD   = 64;
constexpr int FFD  = 3072;
constexpr int RR   = Bc * Nn;   // 4096 rows
}
#define EPSF 1e-5f

typedef unsigned short u16;
typedef __bf16 bf16x8 __attribute__((ext_vector_type(8)));
typedef float  f32x4  __attribute__((ext_vector_type(4)));
typedef u16    u16x8  __attribute__((ext_vector_type(8)));
typedef u16    u16x4  __attribute__((ext_vector_type(4)));

#define GPTR(p) ((const __attribute__((address_space(1))) void*)(p))
#define LPTR(p) ((__attribute__((address_space(3))) void*)(p))

// ---------------- helpers ----------------
__device__ __forceinline__ float fast_exp2(float a) {
  float e;
  asm("v_exp_f32 %0, %1" : "=v"(e) : "v"(a));
  return e;
}
__device__ __forceinline__ float fast_rcp(float x) {
  float r;
  asm("v_rcp_f32 %0, %1" : "=v"(r) : "v"(x));
  return r;
}
__device__ __forceinline__ float geluf(float x) {
  const float u = 0.7978845608028654f * x * (1.0f + 0.044715f * x * x);
  const float e = fast_exp2(u * 2.885390081777927f);
  const float t = (e - 1.0f) * fast_rcp(e + 1.0f);
  return 0.5f * x * (1.0f + t);
}
__device__ __forceinline__ float sigmoidf_(float x) {
  const float e = fast_exp2(-x * 1.4426950408889634f);   // exp(-x)
  return fast_rcp(1.0f + e);
}
__device__ __forceinline__ u16 f2bf(float x) {
  union { float f; unsigned u; } v; v.f = x;
  unsigned r = (v.u + 0x7fffu + ((v.u >> 16) & 1u)) >> 16;
  return (u16)r;
}
__device__ __forceinline__ float bf2f(u16 u) {
  union { unsigned u; float f; } v; v.u = ((unsigned)u) << 16;
  return v.f;
}
// RoPE sin/cos: inv = 10000^(-j/32) via v_exp; angle in revolutions + v_sin/v_cos.
__device__ __forceinline__ void rope_sc(float pos, int j, float* s, float* c) {
  const float e = fast_exp2(-(float)j * 0.41524101186092028f); // log2(1e4)/32
  const float rev = pos * (e * 0.15915494309189535f);          // /2pi
  const float fr = rev - floorf(rev);
  asm("v_sin_f32 %0, %1" : "=v"(*s) : "v"(fr));
  asm("v_cos_f32 %0, %1" : "=v"(*c) : "v"(fr));
}

// ---------------- rmsnorm: one block per row (D=768), float4 + value reuse ----
template<bool BF>
__global__ __launch_bounds__(256) void k_rmsnorm2(const float* __restrict__ in,
                                                  const float* __restrict__ w,
                                                  void* __restrict__ outv) {
  const int row = blockIdx.x;
  const int t = threadIdx.x;
  const float4* x4 = (const float4*)(in + (size_t)row * DM);
  float4 v = make_float4(0.f, 0.f, 0.f, 0.f);
  float ss = 0.f;
  if (t < 192) {
    v = x4[t];
    ss = fmaf(v.x, v.x, fmaf(v.y, v.y, fmaf(v.z, v.z, v.w * v.w)));
  }
  __shared__ float red[5];
#pragma unroll
  for (int off = 32; off > 0; off >>= 1) ss += __shfl_down(ss, off, 64);
  if ((t & 63) == 0) red[t >> 6] = ss;
  __syncthreads();
  if (t == 0) red[4] = red[0] + red[1] + red[2] + red[3];
  __syncthreads();
  const float scale = rsqrtf(red[4] * (1.0f / (float)DM) + EPSF);
  if (t < 192) {
    const float4 wv = ((const float4*)w)[t];
    const float r0 = v.x * scale * wv.x;
    const float r1 = v.y * scale * wv.y;
    const float r2 = v.z * scale * wv.z;
    const float r3 = v.w * scale * wv.w;
    if (BF) {
      u16x4 o; o[0] = f2bf(r0); o[1] = f2bf(r1); o[2] = f2bf(r2); o[3] = f2bf(r3);
      ((u16x4*)outv)[(size_t)row * 192 + t] = o;
    } else {
      ((float4*)outv)[(size_t)row * 192 + t] = make_float4(r0, r1, r2, r3);
    }
  }
}

// ---------------- fused weight prep: all 8 transposes + stats zero, 1 launch --
__device__ __forceinline__ void wt_tile(const float* __restrict__ W,
                                        u16* __restrict__ Wt, int K, int N,
                                        int gx, int r,
                                        u16 (*T)[72], int tid) {
  const int nb = (r % gx) * 64;
  const int kb = (r / gx) * 64;
#pragma unroll
  for (int p = 0; p < 4; ++p) {
    const int rr = p * 16 + (tid >> 4);             // k within tile
    const int c = (tid & 15) * 4;                   // n within tile
    float4 v = *(const float4*)(W + (size_t)(kb + rr) * N + nb + c);
    T[c + 0][rr] = f2bf(v.x); T[c + 1][rr] = f2bf(v.y);
    T[c + 2][rr] = f2bf(v.z); T[c + 3][rr] = f2bf(v.w);
  }
  __syncthreads();
  const int cc = (tid & 7) * 8;
#pragma unroll
  for (int p = 0; p < 2; ++p) {
    const int rr = p * 32 + (tid >> 3);
    *(u16x8*)(Wt + (size_t)(nb + rr) * K + kb + cc) = *(const u16x8*)&T[rr][cc];
  }
}

__global__ __launch_bounds__(256) void k_wt_all(
    const float* w0, u16* o0,   // ff1_w1  768x3072  gx=48 blocks=576
    const float* w1, u16* o1,   // ff1_w2  3072x768  gx=12 blocks=576
    const float* w2, u16* o2,   // qkv     768x2304  gx=36 blocks=432
    const float* w3, u16* o3,   // out     768x768   gx=12 blocks=144
    const float* w4, u16* o4,   // pw1     768x1536  gx=24 blocks=288
    const float* w5, u16* o5,   // pw2     768x768   gx=12 blocks=144
    const float* w6, u16* o6,   // ff2_w1  768x3072  gx=48 blocks=576
    const float* w7, u16* o7,   // ff2_w2  3072x768  gx=12 blocks=576
    float* stats) {             // zero 2*DM floats  blocks=6
  __shared__ __align__(16) u16 T[64][72];
  const int tid = threadIdx.x;
  int r = blockIdx.x;
  if (r < 576) { wt_tile(w0, o0, 768, 3072, 48, r, T, tid); return; } r -= 576;
  if (r < 576) { wt_tile(w1, o1, 3072, 768, 12, r, T, tid); return; } r -= 576;
  if (r < 432) { wt_tile(w2, o2, 768, 2304, 36, r, T, tid); return; } r -= 432;
  if (r < 144) { wt_tile(w3, o3, 768, 768, 12, r, T, tid); return; } r -= 144;
  if (r < 288) { wt_tile(w4, o4, 768, 1536, 24, r, T, tid); return; } r -= 288;
  if (r < 144) { wt_tile(w5, o5, 768, 768, 12, r, T, tid); return; } r -= 144;
  if (r < 576) { wt_tile(w6, o6, 768, 3072, 48, r, T, tid); return; } r -= 576;
  if (r < 576) { wt_tile(w7, o7, 3072, 768, 12, r, T, tid); return; } r -= 576;
  const int idx = r * 256 + tid;
  if (idx < 2 * DM) stats[idx] = 0.f;
}

// ---------------- MFMA GEMM v3: parameterized tile, triple-buffered, 1 barrier/
// K-step, counted vmcnt(LD). C = A @ Wt^T. MODE: 0=+bias,1=gelu,2=0.5+res,3=+res.
// Operand-swapped mfma(bF,aF) -> thread holds 4 consecutive n of one row m.
// LDS dest of global_load_lds is WAVE-UNIFORM base (tid&192); HW adds lane*16.
template<int BM, int BN, int BKt, int MODE, bool OUTBF>
__global__ __launch_bounds__(256) void k_gemm_mfma(const u16* __restrict__ A,
                                                   const u16* __restrict__ Wt,
                                                   const float* __restrict__ bias,
                                                   const float* __restrict__ res,
                                                   void* __restrict__ Cv,
                                                   int K, int Nc) {
  constexpr int CH  = BKt / 8;                 // 16B chunks per row
  constexpr int SWM = CH - 1;                  // swizzle mask
  constexpr int RT  = BM / 32;                 // row tiles per wave
  constexpr int CT  = BN / 32;                 // col tiles per wave
  constexpr int KK  = BKt / 32;                // MFMA-k per step
  constexpr int ACH = BM * BKt / 8 / 256;      // A chunks per thread
  constexpr int BCH = BN * BKt / 8 / 256;      // B chunks per thread
  constexpr int LD  = ACH + BCH;               // glds per thread per stage
  static_assert(LD == 3 || LD == 4, "vmcnt ledger");
  __shared__ __align__(16) u16 As[3][BM * BKt];
  __shared__ __align__(16) u16 Bs[3][BN * BKt];
  const int tid  = threadIdx.x;
  const int lane = tid & 63;
  const int wbase = tid & 192;                 // wave-uniform chunk base part
  const int w    = tid >> 6;
  const int gx = gridDim.x;
  const int nwg = gx * gridDim.y;
  int bid = blockIdx.y * gx + blockIdx.x;
  if ((nwg & 7) == 0) bid = (bid & 7) * (nwg >> 3) + (bid >> 3);
  const int rowBase = (bid / gx) * BM;
  const int colBase = (bid % gx) * BN;
  const int l15 = lane & 15, quad = lane >> 4;
  const int wr = w >> 1, wc = w & 1;
  const int xsw = l15 & SWM;                   // read-side swizzle

  const u16* aS[ACH];
#pragma unroll
  for (int s = 0; s < ACH; ++s) {
    const int c = s * 256 + tid;
    const int r = c / CH;
    const int kc = (c & SWM) ^ (r & SWM);
    aS[s] = A + (size_t)(rowBase + r) * K + kc * 8;
  }
  const u16* bS[BCH];
#pragma unroll
  for (int s = 0; s < BCH; ++s) {
    const int c = s * 256 + tid;
    const int r = c / CH;
    const int kc = (c & SWM) ^ (r & SWM);
    bS[s] = Wt + (size_t)(colBase + r) * K + kc * 8;
  }

  f32x4 acc[RT][CT];
#pragma unroll
  for (int i = 0; i < RT; ++i)
#pragma unroll
    for (int j = 0; j < CT; ++j) acc[i][j] = (f32x4){0.f, 0.f, 0.f, 0.f};

  auto stage = [&](int buf, int k0e) {
#pragma unroll
    for (int s = 0; s < ACH; ++s)
      __builtin_amdgcn_global_load_lds(GPTR(aS[s] + k0e),
          LPTR((char*)As[buf] + (size_t)(s * 256 + wbase) * 16), 16, 0, 0);
#pragma unroll
    for (int s = 0; s < BCH; ++s)
      __builtin_amdgcn_global_load_lds(GPTR(bS[s] + k0e),
          LPTR((char*)Bs[buf] + (size_t)(s * 256 + wbase) * 16), 16, 0, 0);
  };

#define GEMM_STEP(BUF, I, DOSTAGE, LAST)                                           \
  {                                                                                \
    if (LAST) { asm volatile("s_waitcnt vmcnt(0)" ::: "memory"); }                 \
    else if (LD == 3) { asm volatile("s_waitcnt vmcnt(3)" ::: "memory"); }         \
    else { asm volatile("s_waitcnt vmcnt(4)" ::: "memory"); }                      \
    __builtin_amdgcn_s_barrier();                                                  \
    asm volatile("" ::: "memory");                                                 \
    if (DOSTAGE) stage(((BUF) + 2) % 3, ((I) + 2) * BKt);                          \
    const u16* ab = As[BUF];                                                       \
    const u16* bb = Bs[BUF];                                                       \
    _Pragma("unroll")                                                              \
    for (int kk = 0; kk < KK; ++kk) {                                              \
      bf16x8 aF[RT], bF[CT];                                                       \
      _Pragma("unroll")                                                            \
      for (int rt = 0; rt < RT; ++rt) {                                            \
        const int m = wr * (BM / 2) + rt * 16 + l15;                               \
        aF[rt] = *(const bf16x8*)&ab[m * BKt + (((kk * 4 + quad) ^ xsw) * 8)];     \
      }                                                                            \
      _Pragma("unroll")                                                            \
      for (int ct = 0; ct < CT; ++ct) {                                            \
        const int n = wc * (BN / 2) + ct * 16 + l15;                               \
        bF[ct] = *(const bf16x8*)&bb[n * BKt + (((kk * 4 + quad) ^ xsw) * 8)];     \
      }                                                                            \
      _Pragma("unroll")                                                            \
      for (int rt = 0; rt < RT; ++rt)                                              \
        _Pragma("unroll")                                                          \
        for (int ct = 0; ct < CT; ++ct)                                            \
          acc[rt][ct] = __builtin_amdgcn_mfma_f32_16x16x32_bf16(bF[ct], aF[rt],    \
                                                                acc[rt][ct],       \
                                                                0, 0, 0);          \
    }                                                                              \
  }

  const int nsteps = K / BKt;     // 12/24/48 for our shapes -- all %3==0
  stage(0, 0);
  stage(1, BKt);
  int i = 0;
  for (; i < nsteps - 3; i += 3) {
    GEMM_STEP(0, i + 0, true, false);
    GEMM_STEP(1, i + 1, true, false);
    GEMM_STEP(2, i + 2, true, false);
  }
  GEMM_STEP(0, nsteps - 3, true, false);
  GEMM_STEP(1, nsteps - 2, false, false);
  GEMM_STEP(2, nsteps - 1, false, true);
#undef GEMM_STEP

  // epilogue: thread holds n0..n0+3 of row m -> coalesced stores
#pragma unroll
  for (int ct = 0; ct < CT; ++ct) {
    const int n0 = colBase + wc * (BN / 2) + ct * 16 + quad * 4;
    float b0 = 0.f, b1 = 0.f, b2 = 0.f, b3 = 0.f;
    if (bias) {
      const float4 bv = *(const float4*)(bias + n0);
      b0 = bv.x; b1 = bv.y; b2 = bv.z; b3 = bv.w;
    }
#pragma unroll
    for (int rt = 0; rt < RT; ++rt) {
      const int m = rowBase + wr * (BM / 2) + rt * 16 + l15;
      float v0 = acc[rt][ct][0] + b0;
      float v1 = acc[rt][ct][1] + b1;
      float v2 = acc[rt][ct][2] + b2;
      float v3 = acc[rt][ct][3] + b3;
      if (MODE == 1) {
        v0 = geluf(v0); v1 = geluf(v1); v2 = geluf(v2); v3 = geluf(v3);
      } else if (MODE == 2) {
        const float4 rv = *(const float4*)(res + (size_t)m * Nc + n0);
        v0 = 0.5f * v0 + rv.x; v1 = 0.5f * v1 + rv.y;
        v2 = 0.5f * v2 + rv.z; v3 = 0.5f * v3 + rv.w;
      } else if (MODE == 3) {
        const float4 rv = *(const float4*)(res + (size_t)m * Nc + n0);
        v0 += rv.x; v1 += rv.y; v2 += rv.z; v3 += rv.w;
      }
      if (OUTBF) {
        unsigned w0, w1;
        asm("v_cvt_pk_bf16_f32 %0, %1, %2" : "=v"(w0) : "v"(v0), "v"(v1));
        asm("v_cvt_pk_bf16_f32 %0, %1, %2" : "=v"(w1) : "v"(v2), "v"(v3));
        uint2 st; st.x = w0; st.y = w1;
        *(uint2*)((u16*)Cv + (size_t)m * Nc + n0) = st;
      } else {
        *(float4*)((float*)Cv + (size_t)m * Nc + n0) =
            make_float4(v0, v1, v2, v3);
      }
    }
  }
}

// ---------------- fused qkv-post + cache-prep (independent halves, 1 launch) --
// qbf is pre-scaled by 0.125*log2(e) (attn scale + exp2-softmax fold).
__global__ __launch_bounds__(768) void k_qkvcache(const float* __restrict__ qkv,
                                                  const float* __restrict__ cached,
                                                  const float* __restrict__ qw,
                                                  const float* __restrict__ kw,
                                                  u16* __restrict__ qbf,
                                                  u16* __restrict__ krotbf,
                                                  float* __restrict__ kvout) {
  const int tid = threadIdx.x;
  const int h = tid >> 6;
  const int d = tid & 63;
  int r = blockIdx.x;
  if (r < RR) {
    const int b = r >> 11;
    const int n = r & 2047;
    const float* src = qkv + (size_t)r * (3 * DM) + h * 192 + d * 3;
    const float q = src[0], k = src[1], v = src[2];
    float sq = q * q, sk = k * k;
#pragma unroll
    for (int off = 32; off > 0; off >>= 1) {
      sq += __shfl_xor(sq, off, 64);
      sk += __shfl_xor(sk, off, 64);
    }
    const float qs = rsqrtf(sq * (1.0f / 64.0f) + EPSF);
    const float ks = rsqrtf(sk * (1.0f / 64.0f) + EPSF);
    const float qn = q * qs * qw[d];
    const float kn = k * ks * kw[d];
    const size_t kvbase = ((size_t)b * KVL + (CACHE + n)) * (2 * DM) + h * 64 + d;
    kvout[kvbase] = kn;
    kvout[kvbase + DM] = v;
    const int j = d & 31;
    float s, c;
    rope_sc((float)(CACHE + n), j, &s, &c);
    const float oq = __shfl_xor(qn, 32, 64);
    const float ok = __shfl_xor(kn, 32, 64);
    const float rq = (d < 32) ? -oq : oq;
    const float rk = (d < 32) ? -ok : ok;
    qbf[((size_t)r * NH + h) * 64 + d] = f2bf((qn * c + rq * s) * 0.18033688011112042f);
    krotbf[((size_t)(b * KVL + CACHE + n) * NH + h) * 64 + d] = f2bf(kn * c + rk * s);
    return;
  }
  r -= RR;
  const int b = r / CACHE, t = r - b * CACHE;
  const float k = cached[((size_t)r * 2 + 0) * DM + h * 64 + d];
  const float v = cached[((size_t)r * 2 + 1) * DM + h * 64 + d];
  const size_t kb = ((size_t)b * KVL + t) * (2 * DM) + h * 64 + d;
  kvout[kb] = k;
  kvout[kb + DM] = v;
  const int j = d & 31;
  float s, c;
  rope_sc((float)t, j, &s, &c);
  const float ok = __shfl_xor(k, 32, 64);
  const float rk = (d < 32) ? -ok : ok;
  krotbf[((size_t)(b * KVL + t) * NH + h) * 64 + d] = f2bf(k * c + rk * s);
}

// ---------------- V transpose: (B,KVL,H,64) f32 -> vtbf (B,H,64,KVL) bf16 ----
__global__ __launch_bounds__(256) void k_vt(const float* __restrict__ kvout,
                                            u16* __restrict__ vtbf) {
  __shared__ __align__(16) u16 T[64][72];
  const int bh = blockIdx.x / 40;
  const int tb = blockIdx.x % 40;
  const int b = bh / NH, h = bh % NH;
  const int t0 = tb * 64;
  {
    const int tloc = threadIdx.x >> 2;
    const int dg = (threadIdx.x & 3) * 16;
    const float* src = kvout + ((size_t)b * KVL + t0 + tloc) * (2 * DM) + DM + h * 64 + dg;
    float4 v0 = *(const float4*)(src);
    float4 v1 = *(const float4*)(src + 4);
    float4 v2 = *(const float4*)(src + 8);
    float4 v3 = *(const float4*)(src + 12);
    T[dg + 0][tloc] = f2bf(v0.x);  T[dg + 1][tloc] = f2bf(v0.y);
    T[dg + 2][tloc] = f2bf(v0.z);  T[dg + 3][tloc] = f2bf(v0.w);
    T[dg + 4][tloc] = f2bf(v1.x);  T[dg + 5][tloc] = f2bf(v1.y);
    T[dg + 6][tloc] = f2bf(v1.z);  T[dg + 7][tloc] = f2bf(v1.w);
    T[dg + 8][tloc] = f2bf(v2.x);  T[dg + 9][tloc] = f2bf(v2.y);
    T[dg + 10][tloc] = f2bf(v2.z); T[dg + 11][tloc] = f2bf(v2.w);
    T[dg + 12][tloc] = f2bf(v3.x); T[dg + 13][tloc] = f2bf(v3.y);
    T[dg + 14][tloc] = f2bf(v3.z); T[dg + 15][tloc] = f2bf(v3.w);
  }
  __syncthreads();
  const int d = threadIdx.x >> 2;
  const int kg = (threadIdx.x & 3) * 16;
  u16x8 a = *(const u16x8*)&T[d][kg];
  u16x8 b8 = *(const u16x8*)&T[d][kg + 8];
  u16* dst = vtbf + ((size_t)(b * NH + h) * 64 + d) * KVL + t0 + kg;
  *(u16x8*)dst = a;
  *(u16x8*)(dst + 8) = b8;
}

// ---------------- MFMA flash attention v7: 2-wave blocks, 32 q per wave -------
// Each aK/aV LDS fragment is read ONCE and feeds TWO MFMAs (q-halves) -> LDS
// read traffic halves vs 4-wave/16q (LDS was the binding pipe at ~83%).
// P-in-register via K-row bit-perm, triple-buffered K/V, one barrier per tile,
// counted vmcnt(8), exp2 softmax, ones-MFMA l-sum on the matrix pipe.
__global__ __launch_bounds__(128) void k_attn4(const u16* __restrict__ qbf,
                                               const u16* __restrict__ krotbf,
                                               const u16* __restrict__ vtbf,
                                               u16* __restrict__ attnout) {
  __shared__ __align__(16) char smem[49152];
  u16* const KsB = (u16*)smem;                 // [3][64*64] swizzled chunks
  u16* const VsB = (u16*)(smem + 24576);       // [3][64*64] swizzled chunks
  const int tid  = threadIdx.x;                // 0..127
  const int lane = tid & 63;
  const int wid  = tid >> 6;                   // 0..1
  const int bid = blockIdx.x;
  const int swz = (bid & 7) * (768 / 8) + (bid >> 3);
  const int qblk = swz & 31;
  const int bh   = swz >> 5;
  const int b = bh / NH, h = bh % NH;
  const int q0w = qblk * 64 + wid * 32;        // wave covers 32 queries
  const int l15 = lane & 15;
  const int quad = lane >> 4;
  const int sw = l15 & 7;

  // Q fragments: qh in {0,1} selects 16-q half; pre-scaled by 0.125*log2e
  bf16x8 bQ[2][2];
#pragma unroll
  for (int qh = 0; qh < 2; ++qh) {
    const u16* qp = qbf + ((size_t)(b * Nn + q0w + qh * 16 + l15) * NH + h) * 64
                    + quad * 8;
    bQ[qh][0] = *(const bf16x8*)qp;
    bQ[qh][1] = *(const bf16x8*)(qp + 32);
    asm volatile("" :: "v"(*(const f32x4*)&bQ[qh][0]),
                       "v"(*(const f32x4*)&bQ[qh][1]));
  }

  union { u16x8 u; bf16x8 v; } ones_u;
#pragma unroll
  for (int z = 0; z < 8; ++z) ones_u.u[z] = 0x3F80;
  const bf16x8 aOnes = ones_u.v;

  f32x4 O[2][4] = {};     // [qh][ot]: d = ot*16 + quad*4 + r, q = q0w+qh*16+l15
  float lsum[2] = {0.f, 0.f};

  // staging: 8 chunks per thread (4 K + 4 V); chunk c = it*128 + tid
  const u16* kbase = krotbf + ((size_t)b * KVL * NH + h) * 64;
  const u16* vbase = vtbf + ((size_t)(b * NH + h) * 64) * KVL;
  const u16* ksrc[4];
  const u16* vsrc[4];
#pragma unroll
  for (int it = 0; it < 4; ++it) {
    const int c = it * 128 + tid;
    const int r = c >> 3;
    const int kc = (c & 7) ^ (r & 7);
    const int g = (r & 3) | ((r & 0xC) << 1) | ((r & 0x10) >> 2) | (r & 0x20);
    ksrc[it] = kbase + (size_t)g * (NH * 64) + kc * 8;
    vsrc[it] = vbase + (size_t)r * KVL + kc * 8;
  }
  const int wu = tid & 64;        // wave-uniform part of chunk index

  auto stage = [&](int buf, int tile) {
    char* kd = (char*)KsB + buf * 8192;
    char* vd = (char*)VsB + buf * 8192;
    const size_t koff = (size_t)tile * (64 * NH * 64);
    const int voff = tile * 64;
#pragma unroll
    for (int it = 0; it < 4; ++it)
      __builtin_amdgcn_global_load_lds(GPTR(ksrc[it] + koff),
          LPTR(kd + (size_t)(it * 128 + wu) * 16), 16, 0, 0);
#pragma unroll
    for (int it = 0; it < 4; ++it)
      __builtin_amdgcn_global_load_lds(GPTR(vsrc[it] + voff),
          LPTR(vd + (size_t)(it * 128 + wu) * 16), 16, 0, 0);
  };

#define ATTN_TILE(BI, I, DOSTAGE, LAST)                                            \
  {                                                                                \
    if (LAST) { asm volatile("s_waitcnt vmcnt(0)" ::: "memory"); }                 \
    else      { asm volatile("s_waitcnt vmcnt(8)" ::: "memory"); }                 \
    __builtin_amdgcn_s_barrier();                                                  \
    asm volatile("" ::: "memory");                                                 \
    if (DOSTAGE) stage(((BI) + 2) % 3, (I) + 2);                                   \
    const u16* ksc = KsB + (BI) * 4096;                                            \
    const u16* vsc = VsB + (BI) * 4096;                                            \
    unsigned Pq[2][2][4];                                                          \
    _Pragma("unroll")                                                              \
    for (int nt = 0; nt < 4; ++nt) {                                               \
      const int krow = nt * 16 + l15;                                              \
      const bf16x8 aK0 = *(const bf16x8*)&ksc[krow * 64 + ((quad ^ sw) * 8)];      \
      const bf16x8 aK1 = *(const bf16x8*)&ksc[krow * 64 + (((4 + quad) ^ sw) * 8)];\
      _Pragma("unroll")                                                            \
      for (int qh = 0; qh < 2; ++qh) {                                             \
        f32x4 cc = {};                                                             \
        cc = __builtin_amdgcn_mfma_f32_16x16x32_bf16(aK0, bQ[qh][0], cc, 0, 0, 0); \
        cc = __builtin_amdgcn_mfma_f32_16x16x32_bf16(aK1, bQ[qh][1], cc, 0, 0, 0); \
        const float p0 = fast_exp2(cc[0]);                                         \
        const float p1 = fast_exp2(cc[1]);                                         \
        const float p2 = fast_exp2(cc[2]);                                         \
        const float p3 = fast_exp2(cc[3]);                                         \
        asm("v_cvt_pk_bf16_f32 %0, %1, %2"                                         \
            : "=v"(Pq[qh][nt >> 1][(nt & 1) * 2 + 0]) : "v"(p0), "v"(p1));         \
        asm("v_cvt_pk_bf16_f32 %0, %1, %2"                                         \
            : "=v"(Pq[qh][nt >> 1][(nt & 1) * 2 + 1]) : "v"(p2), "v"(p3));         \
      }                                                                            \
    }                                                                              \
    __builtin_amdgcn_s_setprio(1);                                                 \
    f32x4 ccl0 = {}, ccl1 = {};                                                    \
    _Pragma("unroll")                                                              \
    for (int kt = 0; kt < 2; ++kt) {                                               \
      union { unsigned u[4]; bf16x8 v; } pu0, pu1;                                 \
      pu0.u[0] = Pq[0][kt][0]; pu0.u[1] = Pq[0][kt][1];                            \
      pu0.u[2] = Pq[0][kt][2]; pu0.u[3] = Pq[0][kt][3];                            \
      pu1.u[0] = Pq[1][kt][0]; pu1.u[1] = Pq[1][kt][1];                            \
      pu1.u[2] = Pq[1][kt][2]; pu1.u[3] = Pq[1][kt][3];                            \
      ccl0 = __builtin_amdgcn_mfma_f32_16x16x32_bf16(aOnes, pu0.v, ccl0, 0, 0, 0); \
      ccl1 = __builtin_amdgcn_mfma_f32_16x16x32_bf16(aOnes, pu1.v, ccl1, 0, 0, 0); \
      _Pragma("unroll")                                                            \
      for (int ot = 0; ot < 4; ++ot) {                                             \
        const int vrow = ot * 16 + l15;                                            \
        const bf16x8 aV =                                                          \
            *(const bf16x8*)&vsc[vrow * 64 + (((kt * 4 + quad) ^ sw) * 8)];        \
        O[0][ot] = __builtin_amdgcn_mfma_f32_16x16x32_bf16(aV, pu0.v,              \
                                                           O[0][ot], 0, 0, 0);    \
        O[1][ot] = __builtin_amdgcn_mfma_f32_16x16x32_bf16(aV, pu1.v,              \
                                                           O[1][ot], 0, 0, 0);    \
      }                                                                            \
    }                                                                              \
    __builtin_amdgcn_s_setprio(0);                                                 \
    lsum[0] += ccl0[0];                                                            \
    lsum[1] += ccl1[0];                                                            \
  }

  stage(0, 0);
  stage(1, 1);
  for (int j = 0; j < 12; ++j) {
    const int i0 = j * 3;
    ATTN_TILE(0, i0 + 0, true, false);
    ATTN_TILE(1, i0 + 1, true, false);
    ATTN_TILE(2, i0 + 2, true, false);
  }
  ATTN_TILE(0, 36, true, false);
  ATTN_TILE(1, 37, true, false);
  ATTN_TILE(2, 38, false, false);
  ATTN_TILE(0, 39, false, true);
#undef ATTN_TILE

  // every lane holds the FULL l per q-half (ones-MFMA colsum)
  const float il0 = 1.0f / lsum[0];
  const float il1 = 1.0f / lsum[1];
  __builtin_amdgcn_s_barrier();     // both waves done reading Ks/Vs
  asm volatile("" ::: "memory");
  float* const OF  = (float*)smem;             // [64][68] f32 (17408 B)
  float* const ILs = (float*)(smem + 17408);   // [64] f32
  if (quad == 0) {
    ILs[wid * 32 + l15]      = il0;
    ILs[wid * 32 + 16 + l15] = il1;
  }
#pragma unroll
  for (int qh = 0; qh < 2; ++qh) {
    float* of = OF + (size_t)(wid * 32 + qh * 16 + l15) * 68;
#pragma unroll
    for (int ot = 0; ot < 4; ++ot)
      *(f32x4*)&of[ot * 16 + quad * 4] = O[qh][ot];
  }
  asm volatile("s_waitcnt lgkmcnt(0)" ::: "memory");   // wave-private staging
  const int q  = tid >> 1;                 // 0..63 (own wave's rows)
  const int dg = (tid & 1) * 32;
  const float sc = ILs[q];
  const float* srcp = OF + (size_t)q * 68 + dg;
  unsigned wv[16];
#pragma unroll
  for (int i2 = 0; i2 < 16; ++i2) {
    const float a0 = srcp[2 * i2] * sc;
    const float a1 = srcp[2 * i2 + 1] * sc;
    asm("v_cvt_pk_bf16_f32 %0, %1, %2" : "=v"(wv[i2]) : "v"(a0), "v"(a1));
  }
  u16* dst = attnout + ((size_t)(b * Nn + qblk * 64 + q)) * DM + h * 64 + dg;
  uint4 s0; s0.x = wv[0];  s0.y = wv[1];  s0.z = wv[2];  s0.w = wv[3];
  uint4 s1; s1.x = wv[4];  s1.y = wv[5];  s1.z = wv[6];  s1.w = wv[7];
  uint4 s2; s2.x = wv[8];  s2.y = wv[9];  s2.z = wv[10]; s2.w = wv[11];
  uint4 s3; s3.x = wv[12]; s3.y = wv[13]; s3.z = wv[14]; s3.w = wv[15];
  *(uint4*)dst = s0;
  *(uint4*)(dst + 8) = s1;
  *(uint4*)(dst + 16) = s2;
  *(uint4*)(dst + 24) = s3;
}

// ---------------- fused GLU + depthwise conv + BN partial stats ----------------
__global__ __launch_bounds__(256) void k_dwconv2(const u16* __restrict__ pw1,
                                                 const float* __restrict__ w,
                                                 const float* __restrict__ bsd,
                                                 float* __restrict__ out,
                                                 float* __restrict__ stats) {
  __shared__ float S[94][68];
  __shared__ float Wl[31][64];
  const int cb = blockIdx.x * 64;
  const int n0 = blockIdx.y * 64;
  const int b  = blockIdx.z;
  for (int idx = threadIdx.x; idx < 94 * 16; idx += 256) {
    const int r = idx >> 4, cg = (idx & 15) * 4;
    const int n = n0 - 15 + r;
    float4 v = make_float4(0.f, 0.f, 0.f, 0.f);
    if (n >= 0 && n < Nn) {
      const u16* p = pw1 + ((size_t)(b * Nn + n)) * (2 * DM) + cb + cg;
      u16x4 av = *(const u16x4*)(p);
      u16x4 gv = *(const u16x4*)(p + DM);
      v.x = bf2f(av[0]) * sigmoidf_(bf2f(gv[0]));
      v.y = bf2f(av[1]) * sigmoidf_(bf2f(gv[1]));
      v.z = bf2f(av[2]) * sigmoidf_(bf2f(gv[2]));
      v.w = bf2f(av[3]) * sigmoidf_(bf2f(gv[3]));
    }
    *(float4*)&S[r][cg] = v;
  }
  for (int idx = threadIdx.x; idx < 31 * 64; idx += 256) {
    const int c = idx & 63, tap = idx >> 6;
    Wl[tap][c] = w[(size_t)(cb + c) * 31 + tap];
  }
  __syncthreads();

  const int cg  = (threadIdx.x & 15) * 4;
  const int nl0 = threadIdx.x >> 4;
  const float4 b4 = *(const float4*)(bsd + cb + cg);
  float sum[4] = {0.f, 0.f, 0.f, 0.f};
  float sq[4]  = {0.f, 0.f, 0.f, 0.f};
#pragma unroll
  for (int p = 0; p < 4; ++p) {
    const int nl = p * 16 + nl0;
    float a0 = b4.x, a1 = b4.y, a2 = b4.z, a3 = b4.w;
#pragma unroll
    for (int t = 0; t < 31; ++t) {
      const float4 sv = *(const float4*)&S[nl + t][cg];
      const float4 wv = *(const float4*)&Wl[t][cg & 63];
      a0 = fmaf(sv.x, wv.x, a0); a1 = fmaf(sv.y, wv.y, a1);
      a2 = fmaf(sv.z, wv.z, a2); a3 = fmaf(sv.w, wv.w, a3);
    }
    *(float4*)(out + ((size_t)(b * Nn + n0 + nl)) * DM + cb + cg) =
        make_float4(a0, a1, a2, a3);
    sum[0] += a0; sum[1] += a1; sum[2] += a2; sum[3] += a3;
    sq[0] = fmaf(a0, a0, sq[0]); sq[1] = fmaf(a1, a1, sq[1]);
    sq[2] = fmaf(a2, a2, sq[2]); sq[3] = fmaf(a3, a3, sq[3]);
  }
  __syncthreads();
  *(float4*)&S[nl0][cg]      = make_float4(sum[0], sum[1], sum[2], sum[3]);
  *(float4*)&S[16 + nl0][cg] = make_float4(sq[0], sq[1], sq[2], sq[3]);
  __syncthreads();
  if (threadIdx.x < 64) {
    const int c = threadIdx.x;
    float s = 0.f, q = 0.f;
#pragma unroll
    for (int i = 0; i < 16; ++i) { s += S[i][c]; q += S[16 + i][c]; }
    atomicAdd(&stats[cb + c], s);
    atomicAdd(&stats[DM + cb + c], q);
  }
}

__global__ __launch_bounds__(256) void k_bn_apply(const float* __restrict__ x,
                                                  const float* __restrict__ stats,
                                                  const float* __restrict__ g,
                                                  const float* __restrict__ bb,
                                                  u16* __restrict__ out) {
  const int idx = blockIdx.x * 256 + threadIdx.x;
  const int c = idx % DM;
  const float mean = stats[c] * (1.0f / (float)RR);
  const float var = stats[DM + c] * (1.0f / (float)RR) - mean * mean;
  float y = (x[idx] - mean) * rsqrtf(var + EPSF) * g[c] + bb[c];
  out[idx] = f2bf(y * sigmoidf_(y));
}

// ---------------- launch ----------------
extern "C" void kernel_launch(void* const* d_in, const int* in_sizes, int n_in,
                              void* d_out, int out_size, void* d_ws, size_t ws_size,
                              hipStream_t stream) {
  const float* x       = (const float*)d_in[0];
  const float* cached  = (const float*)d_in[4];
  const float* ff1_nw  = (const float*)d_in[5];
  const float* ff1_w1  = (const float*)d_in[6];
  const float* ff1_b1  = (const float*)d_in[7];
  const float* ff1_w2  = (const float*)d_in[8];
  const float* ff1_b2  = (const float*)d_in[9];
  const float* attn_nw = (const float*)d_in[10];
  const float* qkv_w   = (const float*)d_in[11];
  const float* out_w   = (const float*)d_in[12];
  const float* q_nw    = (const float*)d_in[13];
  const float* k_nw    = (const float*)d_in[14];
  const float* conv_nw = (const float*)d_in[15];
  const float* pw1_w   = (const float*)d_in[16];
  const float* pw1_b   = (const float*)d_in[17];
  const float* dw_w    = (const float*)d_in[18];
  const float* dw_b    = (const float*)d_in[19];
  const float* bn_g    = (const float*)d_in[20];
  const float* bn_b    = (const float*)d_in[21];
  const float* pw2_w   = (const float*)d_in[22];
  const float* pw2_b   = (const float*)d_in[23];
  const float* ff2_nw  = (const float*)d_in[24];
  const float* ff2_w1  = (const float*)d_in[25];
  const float* ff2_b1  = (const float*)d_in[26];
  const float* ff2_w2  = (const float*)d_in[27];
  const float* ff2_b2  = (const float*)d_in[28];
  const float* out_nw  = (const float*)d_in[29];

  float* out_x  = (float*)d_out;
  float* out_kv = out_x + (size_t)RR * DM;

  // ---- workspace layout ----
  u16* wt_ff1w1 = (u16*)d_ws;                          // 3072 x 768
  u16* wt_ff1w2 = wt_ff1w1 + (size_t)3072 * 768;       // 768 x 3072
  u16* wt_qkv   = wt_ff1w2 + (size_t)768 * 3072;       // 2304 x 768
  u16* wt_out   = wt_qkv   + (size_t)2304 * 768;       // 768 x 768
  u16* wt_pw1   = wt_out   + (size_t)768 * 768;        // 1536 x 768
  u16* wt_pw2   = wt_pw1   + (size_t)1536 * 768;       // 768 x 768
  u16* wt_ff2w1 = wt_pw2   + (size_t)768 * 768;        // 3072 x 768
  u16* wt_ff2w2 = wt_ff2w1 + (size_t)3072 * 768;       // 768 x 3072
  u16* abuf     = wt_ff2w2 + (size_t)768 * 3072;       // RR x 768 bf16
  u16* hbuf     = abuf + (size_t)RR * DM;              // RR x 3072 bf16
  float* xA     = (float*)(hbuf + (size_t)RR * FFD);   // RR x 768 f32
  float* xB     = xA + (size_t)RR * DM;                // RR x 768 f32
  float* qkvbuf = xB + (size_t)RR * DM;                // RR x 2304 f32
  u16* qbf      = (u16*)(qkvbuf + (size_t)RR * 3 * DM);
  u16* krotbf   = qbf + (size_t)RR * DM;
  u16* vtbf     = krotbf + (size_t)Bc * KVL * DM;
  float* bn_stats = (float*)(vtbf + (size_t)Bc * KVL * DM);
  // aliases (disjoint lifetimes):
  u16* attnout  = (u16*)qkvbuf;                        // RR x 768 bf16
  float* dwout  = qkvbuf;                              // RR x 768 f32 (conv phase)
  u16* bnout    = (u16*)(qkvbuf + (size_t)RR * DM);    // RR x 768 bf16 (conv phase)

  const dim3 blk(256);
  // ---- weight prep + stats zero: ONE launch ----
  k_wt_all<<<3318, blk, 0, stream>>>(ff1_w1, wt_ff1w1, ff1_w2, wt_ff1w2,
                                     qkv_w, wt_qkv, out_w, wt_out,
                                     pw1_w, wt_pw1, pw2_w, wt_pw2,
                                     ff2_w1, wt_ff2w1, ff2_w2, wt_ff2w2,
                                     bn_stats);

  // ---- FF1 ----
  k_rmsnorm2<true><<<RR, blk, 0, stream>>>(x, ff1_nw, abuf);
  k_gemm_mfma<128, 128, 32, 1, true><<<dim3(FFD / 128, RR / 128), blk, 0, stream>>>(
      abuf, wt_ff1w1, ff1_b1, nullptr, hbuf, DM, FFD);
  k_gemm_mfma<64, 64, 64, 2, false><<<dim3(DM / 64, RR / 64), blk, 0, stream>>>(
      hbuf, wt_ff1w2, ff1_b2, x, xA, FFD, DM);
  // ---- Attention ----
  k_rmsnorm2<true><<<RR, blk, 0, stream>>>(xA, attn_nw, abuf);
  k_gemm_mfma<128, 128, 32, 0, false><<<dim3(3 * DM / 128, RR / 128), blk, 0, stream>>>(
      abuf, wt_qkv, nullptr, nullptr, qkvbuf, DM, 3 * DM);
  k_qkvcache<<<RR + Bc * CACHE, 768, 0, stream>>>(qkvbuf, cached, q_nw, k_nw,
                                                  qbf, krotbf, out_kv);
  k_vt<<<Bc * NH * (KVL / 64), blk, 0, stream>>>(out_kv, vtbf);
  k_attn4<<<Bc * NH * (Nn / 64), dim3(128), 0, stream>>>(qbf, krotbf, vtbf, attnout);
  k_gemm_mfma<64, 64, 64, 3, false><<<dim3(DM / 64, RR / 64), blk, 0, stream>>>(
      attnout, wt_out, nullptr, xA, xB, DM, DM);
  // ---- Conv module ----
  k_rmsnorm2<true><<<RR, blk, 0, stream>>>(xB, conv_nw, abuf);
  k_gemm_mfma<64, 128, 32, 0, true><<<dim3(2 * DM / 128, RR / 64), blk, 0, stream>>>(
      abuf, wt_pw1, pw1_b, nullptr, hbuf, DM, 2 * DM);
  k_dwconv2<<<dim3(DM / 64, Nn / 64, Bc), blk, 0, stream>>>(hbuf, dw_w, dw_b,
                                                            dwout, bn_stats);
  k_bn_apply<<<RR * DM / 256, blk, 0, stream>>>(dwout, bn_stats, bn_g, bn_b, bnout);
  k_gemm_mfma<64, 64, 64, 0, false><<<dim3(DM / 64, RR / 64), blk, 0, stream>>>(
      bnout, wt_pw2, pw2_b, nullptr, xA, DM, DM);
  // ---- FF2 ----
  k_rmsnorm2<true><<<RR, blk, 0, stream>>>(xA, ff2_nw, abuf);
  k_gemm_mfma<128, 128, 32, 1, true><<<dim3(FFD / 128, RR / 128), blk, 0, stream>>>(
      abuf, wt_ff2w1, ff2_b1, nullptr, hbuf, DM, FFD);
  k_gemm_mfma<64, 64, 64, 2, false><<<dim3(DM / 64, RR / 64), blk, 0, stream>>>(
      hbuf, wt_ff2w2, ff2_b2, xA, xB, FFD, DM);
  // ---- final norm ----
  k_rmsnorm2<false><<<RR, blk, 0, stream>>>(xB, out_nw, out_x);
}

// Round 12
// 486.321 us; speedup vs baseline: 1.0350x; 1.0350x over previous
//
#include <hip/hip_runtime.h>
#include <hip/hip_bf16.h>
#include <math.h>

// ---------------- constants ----------------
namespace {
constexpr int Bc   = 2;
constexpr int Nn   = 2048;
constexpr int CACHE= 512;
constexpr int KVL  = 2560;      // CACHE + Nn
constexpr int DM   = 768;
constexpr int NH   = 12;
constexpr int HD   = 64;
constexpr int FFD  = 3072;
constexpr int RR   = Bc * Nn;   // 4096 rows
}
#define EPSF 1e-5f

typedef unsigned short u16;
typedef __bf16 bf16x8 __attribute__((ext_vector_type(8)));
typedef float  f32x4  __attribute__((ext_vector_type(4)));
typedef u16    u16x8  __attribute__((ext_vector_type(8)));
typedef u16    u16x4  __attribute__((ext_vector_type(4)));

#define GPTR(p) ((const __attribute__((address_space(1))) void*)(p))
#define LPTR(p) ((__attribute__((address_space(3))) void*)(p))

// ---------------- helpers ----------------
__device__ __forceinline__ float fast_exp2(float a) {
  float e;
  asm("v_exp_f32 %0, %1" : "=v"(e) : "v"(a));
  return e;
}
__device__ __forceinline__ float fast_rcp(float x) {
  float r;
  asm("v_rcp_f32 %0, %1" : "=v"(r) : "v"(x));
  return r;
}
__device__ __forceinline__ float geluf(float x) {
  const float u = 0.7978845608028654f * x * (1.0f + 0.044715f * x * x);
  const float e = fast_exp2(u * 2.885390081777927f);
  const float t = (e - 1.0f) * fast_rcp(e + 1.0f);
  return 0.5f * x * (1.0f + t);
}
__device__ __forceinline__ float sigmoidf_(float x) {
  const float e = fast_exp2(-x * 1.4426950408889634f);   // exp(-x)
  return fast_rcp(1.0f + e);
}
__device__ __forceinline__ u16 f2bf(float x) {
  union { float f; unsigned u; } v; v.f = x;
  unsigned r = (v.u + 0x7fffu + ((v.u >> 16) & 1u)) >> 16;
  return (u16)r;
}
__device__ __forceinline__ float bf2f(u16 u) {
  union { unsigned u; float f; } v; v.u = ((unsigned)u) << 16;
  return v.f;
}
// RoPE sin/cos: inv = 10000^(-j/32) via v_exp; angle in revolutions + v_sin/v_cos.
__device__ __forceinline__ void rope_sc(float pos, int j, float* s, float* c) {
  const float e = fast_exp2(-(float)j * 0.41524101186092028f); // log2(1e4)/32
  const float rev = pos * (e * 0.15915494309189535f);          // /2pi
  const float fr = rev - floorf(rev);
  asm("v_sin_f32 %0, %1" : "=v"(*s) : "v"(fr));
  asm("v_cos_f32 %0, %1" : "=v"(*c) : "v"(fr));
}

// ---------------- rmsnorm: one block per row (D=768), float4 + value reuse ----
template<bool BF>
__global__ __launch_bounds__(256) void k_rmsnorm2(const float* __restrict__ in,
                                                  const float* __restrict__ w,
                                                  void* __restrict__ outv) {
  const int row = blockIdx.x;
  const int t = threadIdx.x;
  const float4* x4 = (const float4*)(in + (size_t)row * DM);
  float4 v = make_float4(0.f, 0.f, 0.f, 0.f);
  float ss = 0.f;
  if (t < 192) {
    v = x4[t];
    ss = fmaf(v.x, v.x, fmaf(v.y, v.y, fmaf(v.z, v.z, v.w * v.w)));
  }
  __shared__ float red[5];
#pragma unroll
  for (int off = 32; off > 0; off >>= 1) ss += __shfl_down(ss, off, 64);
  if ((t & 63) == 0) red[t >> 6] = ss;
  __syncthreads();
  if (t == 0) red[4] = red[0] + red[1] + red[2] + red[3];
  __syncthreads();
  const float scale = rsqrtf(red[4] * (1.0f / (float)DM) + EPSF);
  if (t < 192) {
    const float4 wv = ((const float4*)w)[t];
    const float r0 = v.x * scale * wv.x;
    const float r1 = v.y * scale * wv.y;
    const float r2 = v.z * scale * wv.z;
    const float r3 = v.w * scale * wv.w;
    if (BF) {
      u16x4 o; o[0] = f2bf(r0); o[1] = f2bf(r1); o[2] = f2bf(r2); o[3] = f2bf(r3);
      ((u16x4*)outv)[(size_t)row * 192 + t] = o;
    } else {
      ((float4*)outv)[(size_t)row * 192 + t] = make_float4(r0, r1, r2, r3);
    }
  }
}

// ---------------- fused weight prep: all 8 transposes + stats zero, 1 launch --
__device__ __forceinline__ void wt_tile(const float* __restrict__ W,
                                        u16* __restrict__ Wt, int K, int N,
                                        int gx, int r,
                                        u16 (*T)[72], int tid) {
  const int nb = (r % gx) * 64;
  const int kb = (r / gx) * 64;
#pragma unroll
  for (int p = 0; p < 4; ++p) {
    const int rr = p * 16 + (tid >> 4);             // k within tile
    const int c = (tid & 15) * 4;                   // n within tile
    float4 v = *(const float4*)(W + (size_t)(kb + rr) * N + nb + c);
    T[c + 0][rr] = f2bf(v.x); T[c + 1][rr] = f2bf(v.y);
    T[c + 2][rr] = f2bf(v.z); T[c + 3][rr] = f2bf(v.w);
  }
  __syncthreads();
  const int cc = (tid & 7) * 8;
#pragma unroll
  for (int p = 0; p < 2; ++p) {
    const int rr = p * 32 + (tid >> 3);
    *(u16x8*)(Wt + (size_t)(nb + rr) * K + kb + cc) = *(const u16x8*)&T[rr][cc];
  }
}

__global__ __launch_bounds__(256) void k_wt_all(
    const float* w0, u16* o0,   // ff1_w1  768x3072  gx=48 blocks=576
    const float* w1, u16* o1,   // ff1_w2  3072x768  gx=12 blocks=576
    const float* w2, u16* o2,   // qkv     768x2304  gx=36 blocks=432
    const float* w3, u16* o3,   // out     768x768   gx=12 blocks=144
    const float* w4, u16* o4,   // pw1     768x1536  gx=24 blocks=288
    const float* w5, u16* o5,   // pw2     768x768   gx=12 blocks=144
    const float* w6, u16* o6,   // ff2_w1  768x3072  gx=48 blocks=576
    const float* w7, u16* o7,   // ff2_w2  3072x768  gx=12 blocks=576
    float* stats) {             // zero 2*DM floats  blocks=6
  __shared__ __align__(16) u16 T[64][72];
  const int tid = threadIdx.x;
  int r = blockIdx.x;
  if (r < 576) { wt_tile(w0, o0, 768, 3072, 48, r, T, tid); return; } r -= 576;
  if (r < 576) { wt_tile(w1, o1, 3072, 768, 12, r, T, tid); return; } r -= 576;
  if (r < 432) { wt_tile(w2, o2, 768, 2304, 36, r, T, tid); return; } r -= 432;
  if (r < 144) { wt_tile(w3, o3, 768, 768, 12, r, T, tid); return; } r -= 144;
  if (r < 288) { wt_tile(w4, o4, 768, 1536, 24, r, T, tid); return; } r -= 288;
  if (r < 144) { wt_tile(w5, o5, 768, 768, 12, r, T, tid); return; } r -= 144;
  if (r < 576) { wt_tile(w6, o6, 768, 3072, 48, r, T, tid); return; } r -= 576;
  if (r < 576) { wt_tile(w7, o7, 3072, 768, 12, r, T, tid); return; } r -= 576;
  const int idx = r * 256 + tid;
  if (idx < 2 * DM) stats[idx] = 0.f;
}

// ---------------- MFMA GEMM v3: parameterized tile, triple-buffered, 1 barrier/
// K-step, counted vmcnt(LD). C = A @ Wt^T. MODE: 0=+bias,1=gelu,2=0.5+res,3=+res.
// Operand-swapped mfma(bF,aF) -> thread holds 4 consecutive n of one row m.
// LDS dest of global_load_lds is WAVE-UNIFORM base (tid&192); HW adds lane*16.
template<int BM, int BN, int BKt, int MODE, bool OUTBF>
__global__ __launch_bounds__(256) void k_gemm_mfma(const u16* __restrict__ A,
                                                   const u16* __restrict__ Wt,
                                                   const float* __restrict__ bias,
                                                   const float* __restrict__ res,
                                                   void* __restrict__ Cv,
                                                   int K, int Nc) {
  constexpr int CH  = BKt / 8;                 // 16B chunks per row
  constexpr int SWM = CH - 1;                  // swizzle mask
  constexpr int RT  = BM / 32;                 // row tiles per wave
  constexpr int CT  = BN / 32;                 // col tiles per wave
  constexpr int KK  = BKt / 32;                // MFMA-k per step
  constexpr int ACH = BM * BKt / 8 / 256;      // A chunks per thread
  constexpr int BCH = BN * BKt / 8 / 256;      // B chunks per thread
  constexpr int LD  = ACH + BCH;               // glds per thread per stage
  static_assert(LD == 3 || LD == 4, "vmcnt ledger");
  __shared__ __align__(16) u16 As[3][BM * BKt];
  __shared__ __align__(16) u16 Bs[3][BN * BKt];
  const int tid  = threadIdx.x;
  const int lane = tid & 63;
  const int wbase = tid & 192;                 // wave-uniform chunk base part
  const int w    = tid >> 6;
  const int gx = gridDim.x;
  const int nwg = gx * gridDim.y;
  int bid = blockIdx.y * gx + blockIdx.x;
  if ((nwg & 7) == 0) bid = (bid & 7) * (nwg >> 3) + (bid >> 3);
  const int rowBase = (bid / gx) * BM;
  const int colBase = (bid % gx) * BN;
  const int l15 = lane & 15, quad = lane >> 4;
  const int wr = w >> 1, wc = w & 1;
  const int xsw = l15 & SWM;                   // read-side swizzle

  const u16* aS[ACH];
#pragma unroll
  for (int s = 0; s < ACH; ++s) {
    const int c = s * 256 + tid;
    const int r = c / CH;
    const int kc = (c & SWM) ^ (r & SWM);
    aS[s] = A + (size_t)(rowBase + r) * K + kc * 8;
  }
  const u16* bS[BCH];
#pragma unroll
  for (int s = 0; s < BCH; ++s) {
    const int c = s * 256 + tid;
    const int r = c / CH;
    const int kc = (c & SWM) ^ (r & SWM);
    bS[s] = Wt + (size_t)(colBase + r) * K + kc * 8;
  }

  f32x4 acc[RT][CT];
#pragma unroll
  for (int i = 0; i < RT; ++i)
#pragma unroll
    for (int j = 0; j < CT; ++j) acc[i][j] = (f32x4){0.f, 0.f, 0.f, 0.f};

  auto stage = [&](int buf, int k0e) {
#pragma unroll
    for (int s = 0; s < ACH; ++s)
      __builtin_amdgcn_global_load_lds(GPTR(aS[s] + k0e),
          LPTR((char*)As[buf] + (size_t)(s * 256 + wbase) * 16), 16, 0, 0);
#pragma unroll
    for (int s = 0; s < BCH; ++s)
      __builtin_amdgcn_global_load_lds(GPTR(bS[s] + k0e),
          LPTR((char*)Bs[buf] + (size_t)(s * 256 + wbase) * 16), 16, 0, 0);
  };

#define GEMM_STEP(BUF, I, DOSTAGE, LAST)                                           \
  {                                                                                \
    if (LAST) { asm volatile("s_waitcnt vmcnt(0)" ::: "memory"); }                 \
    else if (LD == 3) { asm volatile("s_waitcnt vmcnt(3)" ::: "memory"); }         \
    else { asm volatile("s_waitcnt vmcnt(4)" ::: "memory"); }                      \
    __builtin_amdgcn_s_barrier();                                                  \
    asm volatile("" ::: "memory");                                                 \
    if (DOSTAGE) stage(((BUF) + 2) % 3, ((I) + 2) * BKt);                          \
    const u16* ab = As[BUF];                                                       \
    const u16* bb = Bs[BUF];                                                       \
    _Pragma("unroll")                                                              \
    for (int kk = 0; kk < KK; ++kk) {                                              \
      bf16x8 aF[RT], bF[CT];                                                       \
      _Pragma("unroll")                                                            \
      for (int rt = 0; rt < RT; ++rt) {                                            \
        const int m = wr * (BM / 2) + rt * 16 + l15;                               \
        aF[rt] = *(const bf16x8*)&ab[m * BKt + (((kk * 4 + quad) ^ xsw) * 8)];     \
      }                                                                            \
      _Pragma("unroll")                                                            \
      for (int ct = 0; ct < CT; ++ct) {                                            \
        const int n = wc * (BN / 2) + ct * 16 + l15;                               \
        bF[ct] = *(const bf16x8*)&bb[n * BKt + (((kk * 4 + quad) ^ xsw) * 8)];     \
      }                                                                            \
      _Pragma("unroll")                                                            \
      for (int rt = 0; rt < RT; ++rt)                                              \
        _Pragma("unroll")                                                          \
        for (int ct = 0; ct < CT; ++ct)                                            \
          acc[rt][ct] = __builtin_amdgcn_mfma_f32_16x16x32_bf16(bF[ct], aF[rt],    \
                                                                acc[rt][ct],       \
                                                                0, 0, 0);          \
    }                                                                              \
  }

  const int nsteps = K / BKt;     // 12/24/48 for our shapes -- all %3==0
  stage(0, 0);
  stage(1, BKt);
  int i = 0;
  for (; i < nsteps - 3; i += 3) {
    GEMM_STEP(0, i + 0, true, false);
    GEMM_STEP(1, i + 1, true, false);
    GEMM_STEP(2, i + 2, true, false);
  }
  GEMM_STEP(0, nsteps - 3, true, false);
  GEMM_STEP(1, nsteps - 2, false, false);
  GEMM_STEP(2, nsteps - 1, false, true);
#undef GEMM_STEP

  // epilogue: thread holds n0..n0+3 of row m -> coalesced stores
#pragma unroll
  for (int ct = 0; ct < CT; ++ct) {
    const int n0 = colBase + wc * (BN / 2) + ct * 16 + quad * 4;
    float b0 = 0.f, b1 = 0.f, b2 = 0.f, b3 = 0.f;
    if (bias) {
      const float4 bv = *(const float4*)(bias + n0);
      b0 = bv.x; b1 = bv.y; b2 = bv.z; b3 = bv.w;
    }
#pragma unroll
    for (int rt = 0; rt < RT; ++rt) {
      const int m = rowBase + wr * (BM / 2) + rt * 16 + l15;
      float v0 = acc[rt][ct][0] + b0;
      float v1 = acc[rt][ct][1] + b1;
      float v2 = acc[rt][ct][2] + b2;
      float v3 = acc[rt][ct][3] + b3;
      if (MODE == 1) {
        v0 = geluf(v0); v1 = geluf(v1); v2 = geluf(v2); v3 = geluf(v3);
      } else if (MODE == 2) {
        const float4 rv = *(const float4*)(res + (size_t)m * Nc + n0);
        v0 = 0.5f * v0 + rv.x; v1 = 0.5f * v1 + rv.y;
        v2 = 0.5f * v2 + rv.z; v3 = 0.5f * v3 + rv.w;
      } else if (MODE == 3) {
        const float4 rv = *(const float4*)(res + (size_t)m * Nc + n0);
        v0 += rv.x; v1 += rv.y; v2 += rv.z; v3 += rv.w;
      }
      if (OUTBF) {
        unsigned w0, w1;
        asm("v_cvt_pk_bf16_f32 %0, %1, %2" : "=v"(w0) : "v"(v0), "v"(v1));
        asm("v_cvt_pk_bf16_f32 %0, %1, %2" : "=v"(w1) : "v"(v2), "v"(v3));
        uint2 st; st.x = w0; st.y = w1;
        *(uint2*)((u16*)Cv + (size_t)m * Nc + n0) = st;
      } else {
        *(float4*)((float*)Cv + (size_t)m * Nc + n0) =
            make_float4(v0, v1, v2, v3);
      }
    }
  }
}

// ---------------- fused qkv-post + cache-prep (independent halves, 1 launch) --
// qbf is pre-scaled by 0.125*log2(e) (attn scale + exp2-softmax fold).
__global__ __launch_bounds__(768) void k_qkvcache(const float* __restrict__ qkv,
                                                  const float* __restrict__ cached,
                                                  const float* __restrict__ qw,
                                                  const float* __restrict__ kw,
                                                  u16* __restrict__ qbf,
                                                  u16* __restrict__ krotbf,
                                                  float* __restrict__ kvout) {
  const int tid = threadIdx.x;
  const int h = tid >> 6;
  const int d = tid & 63;
  int r = blockIdx.x;
  if (r < RR) {
    const int b = r >> 11;
    const int n = r & 2047;
    const float* src = qkv + (size_t)r * (3 * DM) + h * 192 + d * 3;
    const float q = src[0], k = src[1], v = src[2];
    float sq = q * q, sk = k * k;
#pragma unroll
    for (int off = 32; off > 0; off >>= 1) {
      sq += __shfl_xor(sq, off, 64);
      sk += __shfl_xor(sk, off, 64);
    }
    const float qs = rsqrtf(sq * (1.0f / 64.0f) + EPSF);
    const float ks = rsqrtf(sk * (1.0f / 64.0f) + EPSF);
    const float qn = q * qs * qw[d];
    const float kn = k * ks * kw[d];
    const size_t kvbase = ((size_t)b * KVL + (CACHE + n)) * (2 * DM) + h * 64 + d;
    kvout[kvbase] = kn;
    kvout[kvbase + DM] = v;
    const int j = d & 31;
    float s, c;
    rope_sc((float)(CACHE + n), j, &s, &c);
    const float oq = __shfl_xor(qn, 32, 64);
    const float ok = __shfl_xor(kn, 32, 64);
    const float rq = (d < 32) ? -oq : oq;
    const float rk = (d < 32) ? -ok : ok;
    qbf[((size_t)r * NH + h) * 64 + d] = f2bf((qn * c + rq * s) * 0.18033688011112042f);
    krotbf[((size_t)(b * KVL + CACHE + n) * NH + h) * 64 + d] = f2bf(kn * c + rk * s);
    return;
  }
  r -= RR;
  const int b = r / CACHE, t = r - b * CACHE;
  const float k = cached[((size_t)r * 2 + 0) * DM + h * 64 + d];
  const float v = cached[((size_t)r * 2 + 1) * DM + h * 64 + d];
  const size_t kb = ((size_t)b * KVL + t) * (2 * DM) + h * 64 + d;
  kvout[kb] = k;
  kvout[kb + DM] = v;
  const int j = d & 31;
  float s, c;
  rope_sc((float)t, j, &s, &c);
  const float ok = __shfl_xor(k, 32, 64);
  const float rk = (d < 32) ? -ok : ok;
  krotbf[((size_t)(b * KVL + t) * NH + h) * 64 + d] = f2bf(k * c + rk * s);
}

// ---------------- V transpose: (B,KVL,H,64) f32 -> vtbf (B,H,64,KVL) bf16 ----
__global__ __launch_bounds__(256) void k_vt(const float* __restrict__ kvout,
                                            u16* __restrict__ vtbf) {
  __shared__ __align__(16) u16 T[64][72];
  const int bh = blockIdx.x / 40;
  const int tb = blockIdx.x % 40;
  const int b = bh / NH, h = bh % NH;
  const int t0 = tb * 64;
  {
    const int tloc = threadIdx.x >> 2;
    const int dg = (threadIdx.x & 3) * 16;
    const float* src = kvout + ((size_t)b * KVL + t0 + tloc) * (2 * DM) + DM + h * 64 + dg;
    float4 v0 = *(const float4*)(src);
    float4 v1 = *(const float4*)(src + 4);
    float4 v2 = *(const float4*)(src + 8);
    float4 v3 = *(const float4*)(src + 12);
    T[dg + 0][tloc] = f2bf(v0.x);  T[dg + 1][tloc] = f2bf(v0.y);
    T[dg + 2][tloc] = f2bf(v0.z);  T[dg + 3][tloc] = f2bf(v0.w);
    T[dg + 4][tloc] = f2bf(v1.x);  T[dg + 5][tloc] = f2bf(v1.y);
    T[dg + 6][tloc] = f2bf(v1.z);  T[dg + 7][tloc] = f2bf(v1.w);
    T[dg + 8][tloc] = f2bf(v2.x);  T[dg + 9][tloc] = f2bf(v2.y);
    T[dg + 10][tloc] = f2bf(v2.z); T[dg + 11][tloc] = f2bf(v2.w);
    T[dg + 12][tloc] = f2bf(v3.x); T[dg + 13][tloc] = f2bf(v3.y);
    T[dg + 14][tloc] = f2bf(v3.z); T[dg + 15][tloc] = f2bf(v3.w);
  }
  __syncthreads();
  const int d = threadIdx.x >> 2;
  const int kg = (threadIdx.x & 3) * 16;
  u16x8 a = *(const u16x8*)&T[d][kg];
  u16x8 b8 = *(const u16x8*)&T[d][kg + 8];
  u16* dst = vtbf + ((size_t)(b * NH + h) * 64 + d) * KVL + t0 + kg;
  *(u16x8*)dst = a;
  *(u16x8*)(dst + 8) = b8;
}

// ---------------- MFMA flash attention v6 (verified best: 4-wave/16q) --------
// P-in-register via K-row bit-perm at staging; triple-buffered K/V, one barrier
// per tile, counted vmcnt(4); exp2 softmax. l accumulated on the MATRIX pipe
// via A=ones MFMA over the same P fragment.
__global__ __launch_bounds__(256) void k_attn3(const u16* __restrict__ qbf,
                                               const u16* __restrict__ krotbf,
                                               const u16* __restrict__ vtbf,
                                               u16* __restrict__ attnout) {
  __shared__ __align__(16) char smem[49152];
  u16* const KsB = (u16*)smem;                 // [3][64*64] swizzled chunks
  u16* const VsB = (u16*)(smem + 24576);       // [3][64*64] swizzled chunks
  const int lane = threadIdx.x & 63;
  const int wid  = threadIdx.x >> 6;
  const int bid = blockIdx.x;
  const int swz = (bid & 7) * (768 / 8) + (bid >> 3);
  const int qblk = swz & 31;
  const int bh   = swz >> 5;
  const int b = bh / NH, h = bh % NH;
  const int q0 = qblk * 64 + wid * 16;
  const int l15 = lane & 15;
  const int quad = lane >> 4;
  const int sw = l15 & 7;

  const u16* qp = qbf + ((size_t)(b * Nn + q0 + l15) * NH + h) * 64 + quad * 8;
  const bf16x8 bQ0 = *(const bf16x8*)qp;
  const bf16x8 bQ1 = *(const bf16x8*)(qp + 32);
  asm volatile("" :: "v"(*(const f32x4*)&bQ0), "v"(*(const f32x4*)&bQ1));

  // all-ones A fragment (bf16 1.0 = 0x3F80) for the l-sum MFMA
  union { u16x8 u; bf16x8 v; } ones_u;
#pragma unroll
  for (int z = 0; z < 8; ++z) ones_u.u[z] = 0x3F80;
  const bf16x8 aOnes = ones_u.v;

  f32x4 O[4] = {};        // O^T: d = ot*16 + quad*4 + r, q = l15
  float l_lane = 0.f;

  const int c0 = (wid * 2 + 0) * 64 + lane;
  const int c1 = (wid * 2 + 1) * 64 + lane;
  const int r0 = c0 >> 3, kc0 = (c0 & 7) ^ (r0 & 7);
  const int r1 = c1 >> 3, kc1 = (c1 & 7) ^ (r1 & 7);
  const int g0 = (r0 & 3) | ((r0 & 0xC) << 1) | ((r0 & 0x10) >> 2) | (r0 & 0x20);
  const int g1 = (r1 & 3) | ((r1 & 0xC) << 1) | ((r1 & 0x10) >> 2) | (r1 & 0x20);
  const u16* kbase = krotbf + ((size_t)b * KVL * NH + h) * 64;
  const u16* vbase = vtbf + ((size_t)(b * NH + h) * 64) * KVL;
  const u16* ksrc0 = kbase + (size_t)g0 * (NH * 64) + kc0 * 8;
  const u16* ksrc1 = kbase + (size_t)g1 * (NH * 64) + kc1 * 8;
  const u16* vsrc0 = vbase + (size_t)r0 * KVL + kc0 * 8;
  const u16* vsrc1 = vbase + (size_t)r1 * KVL + kc1 * 8;
  const size_t kd0 = (size_t)(wid * 2 + 0) * 1024;
  const size_t kd1 = (size_t)(wid * 2 + 1) * 1024;

  auto stage = [&](int buf, int tile) {
    char* kd = (char*)KsB + buf * 8192;
    char* vd = (char*)VsB + buf * 8192;
    const size_t koff = (size_t)tile * (64 * NH * 64);
    const int voff = tile * 64;
    __builtin_amdgcn_global_load_lds(GPTR(ksrc0 + koff), LPTR(kd + kd0), 16, 0, 0);
    __builtin_amdgcn_global_load_lds(GPTR(vsrc0 + voff), LPTR(vd + kd0), 16, 0, 0);
    __builtin_amdgcn_global_load_lds(GPTR(ksrc1 + koff), LPTR(kd + kd1), 16, 0, 0);
    __builtin_amdgcn_global_load_lds(GPTR(vsrc1 + voff), LPTR(vd + kd1), 16, 0, 0);
  };

#define ATTN_TILE(BI, I, DOSTAGE, LAST)                                            \
  {                                                                                \
    if (LAST) { asm volatile("s_waitcnt vmcnt(0)" ::: "memory"); }                 \
    else      { asm volatile("s_waitcnt vmcnt(4)" ::: "memory"); }                 \
    __builtin_amdgcn_s_barrier();                                                  \
    asm volatile("" ::: "memory");                                                 \
    if (DOSTAGE) stage(((BI) + 2) % 3, (I) + 2);                                   \
    const u16* ksc = KsB + (BI) * 4096;                                            \
    const u16* vsc = VsB + (BI) * 4096;                                            \
    unsigned Pr[2][4];                                                             \
    _Pragma("unroll")                                                              \
    for (int nt = 0; nt < 4; ++nt) {                                               \
      const int krow = nt * 16 + l15;                                              \
      const bf16x8 aK0 = *(const bf16x8*)&ksc[krow * 64 + ((quad ^ sw) * 8)];      \
      const bf16x8 aK1 = *(const bf16x8*)&ksc[krow * 64 + (((4 + quad) ^ sw) * 8)];\
      f32x4 cc = {};                                                               \
      cc = __builtin_amdgcn_mfma_f32_16x16x32_bf16(aK0, bQ0, cc, 0, 0, 0);         \
      cc = __builtin_amdgcn_mfma_f32_16x16x32_bf16(aK1, bQ1, cc, 0, 0, 0);         \
      const float p0 = fast_exp2(cc[0]);                                           \
      const float p1 = fast_exp2(cc[1]);                                           \
      const float p2 = fast_exp2(cc[2]);                                           \
      const float p3 = fast_exp2(cc[3]);                                           \
      asm("v_cvt_pk_bf16_f32 %0, %1, %2"                                           \
          : "=v"(Pr[nt >> 1][(nt & 1) * 2 + 0]) : "v"(p0), "v"(p1));               \
      asm("v_cvt_pk_bf16_f32 %0, %1, %2"                                           \
          : "=v"(Pr[nt >> 1][(nt & 1) * 2 + 1]) : "v"(p2), "v"(p3));               \
    }                                                                              \
    __builtin_amdgcn_s_setprio(1);                                                 \
    f32x4 ccl = {};                                                                \
    _Pragma("unroll")                                                              \
    for (int kt = 0; kt < 2; ++kt) {                                               \
      union { unsigned u[4]; bf16x8 v; } pu;                                       \
      pu.u[0] = Pr[kt][0]; pu.u[1] = Pr[kt][1];                                    \
      pu.u[2] = Pr[kt][2]; pu.u[3] = Pr[kt][3];                                    \
      ccl = __builtin_amdgcn_mfma_f32_16x16x32_bf16(aOnes, pu.v, ccl, 0, 0, 0);    \
      _Pragma("unroll")                                                            \
      for (int ot = 0; ot < 4; ++ot) {                                             \
        const int vrow = ot * 16 + l15;                                            \
        const bf16x8 aV =                                                          \
            *(const bf16x8*)&vsc[vrow * 64 + (((kt * 4 + quad) ^ sw) * 8)];        \
        O[ot] = __builtin_amdgcn_mfma_f32_16x16x32_bf16(aV, pu.v, O[ot], 0, 0, 0); \
      }                                                                            \
    }                                                                              \
    __builtin_amdgcn_s_setprio(0);                                                 \
    l_lane += ccl[0];                                                              \
  }

  stage(0, 0);
  stage(1, 1);
  for (int j = 0; j < 12; ++j) {
    const int i0 = j * 3;
    ATTN_TILE(0, i0 + 0, true, false);
    ATTN_TILE(1, i0 + 1, true, false);
    ATTN_TILE(2, i0 + 2, true, false);
  }
  ATTN_TILE(0, 36, true, false);
  ATTN_TILE(1, 37, true, false);
  ATTN_TILE(2, 38, false, false);
  ATTN_TILE(0, 39, false, true);
#undef ATTN_TILE

  // every lane already holds the FULL l for q = q0+l15 (ones-MFMA colsum)
  const float il = 1.0f / l_lane;
  __builtin_amdgcn_s_barrier();
  asm volatile("" ::: "memory");
  float* const OF  = (float*)smem;             // [4][16][68] f32 (17408 B)
  float* const ILs = (float*)(smem + 17408);   // [4][16] f32
  if (quad == 0) ILs[wid * 16 + l15] = il;
  float* of = OF + (size_t)(wid * 16 + l15) * 68;
#pragma unroll
  for (int ot = 0; ot < 4; ++ot)
    *(f32x4*)&of[ot * 16 + quad * 4] = O[ot];
  asm volatile("s_waitcnt lgkmcnt(0)" ::: "memory");
  const int q  = lane >> 2;
  const int dg = (lane & 3) * 16;
  const float sc = ILs[wid * 16 + q];
  const float* srcp = OF + (size_t)(wid * 16 + q) * 68 + dg;
  unsigned wv[8];
#pragma unroll
  for (int i2 = 0; i2 < 8; ++i2) {
    const float a0 = srcp[2 * i2] * sc;
    const float a1 = srcp[2 * i2 + 1] * sc;
    asm("v_cvt_pk_bf16_f32 %0, %1, %2" : "=v"(wv[i2]) : "v"(a0), "v"(a1));
  }
  u16* dst = attnout + ((size_t)(b * Nn + q0 + q)) * DM + h * 64 + dg;
  uint4 s0; s0.x = wv[0]; s0.y = wv[1]; s0.z = wv[2]; s0.w = wv[3];
  uint4 s1; s1.x = wv[4]; s1.y = wv[5]; s1.z = wv[6]; s1.w = wv[7];
  *(uint4*)dst = s0;
  *(uint4*)(dst + 8) = s1;
}

// ---------------- fused GLU + depthwise conv + BN partial stats ----------------
__global__ __launch_bounds__(256) void k_dwconv2(const u16* __restrict__ pw1,
                                                 const float* __restrict__ w,
                                                 const float* __restrict__ bsd,
                                                 float* __restrict__ out,
                                                 float* __restrict__ stats) {
  __shared__ float S[94][68];
  __shared__ float Wl[31][64];
  const int cb = blockIdx.x * 64;
  const int n0 = blockIdx.y * 64;
  const int b  = blockIdx.z;
  for (int idx = threadIdx.x; idx < 94 * 16; idx += 256) {
    const int r = idx >> 4, cg = (idx & 15) * 4;
    const int n = n0 - 15 + r;
    float4 v = make_float4(0.f, 0.f, 0.f, 0.f);
    if (n >= 0 && n < Nn) {
      const u16* p = pw1 + ((size_t)(b * Nn + n)) * (2 * DM) + cb + cg;
      u16x4 av = *(const u16x4*)(p);
      u16x4 gv = *(const u16x4*)(p + DM);
      v.x = bf2f(av[0]) * sigmoidf_(bf2f(gv[0]));
      v.y = bf2f(av[1]) * sigmoidf_(bf2f(gv[1]));
      v.z = bf2f(av[2]) * sigmoidf_(bf2f(gv[2]));
      v.w = bf2f(av[3]) * sigmoidf_(bf2f(gv[3]));
    }
    *(float4*)&S[r][cg] = v;
  }
  for (int idx = threadIdx.x; idx < 31 * 64; idx += 256) {
    const int c = idx & 63, tap = idx >> 6;
    Wl[tap][c] = w[(size_t)(cb + c) * 31 + tap];
  }
  __syncthreads();

  const int cg  = (threadIdx.x & 15) * 4;
  const int nl0 = threadIdx.x >> 4;
  const float4 b4 = *(const float4*)(bsd + cb + cg);
  float sum[4] = {0.f, 0.f, 0.f, 0.f};
  float sq[4]  = {0.f, 0.f, 0.f, 0.f};
#pragma unroll
  for (int p = 0; p < 4; ++p) {
    const int nl = p * 16 + nl0;
    float a0 = b4.x, a1 = b4.y, a2 = b4.z, a3 = b4.w;
#pragma unroll
    for (int t = 0; t < 31; ++t) {
      const float4 sv = *(const float4*)&S[nl + t][cg];
      const float4 wv = *(const float4*)&Wl[t][cg & 63];
      a0 = fmaf(sv.x, wv.x, a0); a1 = fmaf(sv.y, wv.y, a1);
      a2 = fmaf(sv.z, wv.z, a2); a3 = fmaf(sv.w, wv.w, a3);
    }
    *(float4*)(out + ((size_t)(b * Nn + n0 + nl)) * DM + cb + cg) =
        make_float4(a0, a1, a2, a3);
    sum[0] += a0; sum[1] += a1; sum[2] += a2; sum[3] += a3;
    sq[0] = fmaf(a0, a0, sq[0]); sq[1] = fmaf(a1, a1, sq[1]);
    sq[2] = fmaf(a2, a2, sq[2]); sq[3] = fmaf(a3, a3, sq[3]);
  }
  __syncthreads();
  *(float4*)&S[nl0][cg]      = make_float4(sum[0], sum[1], sum[2], sum[3]);
  *(float4*)&S[16 + nl0][cg] = make_float4(sq[0], sq[1], sq[2], sq[3]);
  __syncthreads();
  if (threadIdx.x < 64) {
    const int c = threadIdx.x;
    float s = 0.f, q = 0.f;
#pragma unroll
    for (int i = 0; i < 16; ++i) { s += S[i][c]; q += S[16 + i][c]; }
    atomicAdd(&stats[cb + c], s);
    atomicAdd(&stats[DM + cb + c], q);
  }
}

__global__ __launch_bounds__(256) void k_bn_apply(const float* __restrict__ x,
                                                  const float* __restrict__ stats,
                                                  const float* __restrict__ g,
                                                  const float* __restrict__ bb,
                                                  u16* __restrict__ out) {
  const int idx = blockIdx.x * 256 + threadIdx.x;
  const int c = idx % DM;
  const float mean = stats[c] * (1.0f / (float)RR);
  const float var = stats[DM + c] * (1.0f / (float)RR) - mean * mean;
  float y = (x[idx] - mean) * rsqrtf(var + EPSF) * g[c] + bb[c];
  out[idx] = f2bf(y * sigmoidf_(y));
}

// ---------------- launch ----------------
extern "C" void kernel_launch(void* const* d_in, const int* in_sizes, int n_in,
                              void* d_out, int out_size, void* d_ws, size_t ws_size,
                              hipStream_t stream) {
  const float* x       = (const float*)d_in[0];
  const float* cached  = (const float*)d_in[4];
  const float* ff1_nw  = (const float*)d_in[5];
  const float* ff1_w1  = (const float*)d_in[6];
  const float* ff1_b1  = (const float*)d_in[7];
  const float* ff1_w2  = (const float*)d_in[8];
  const float* ff1_b2  = (const float*)d_in[9];
  const float* attn_nw = (const float*)d_in[10];
  const float* qkv_w   = (const float*)d_in[11];
  const float* out_w   = (const float*)d_in[12];
  const float* q_nw    = (const float*)d_in[13];
  const float* k_nw    = (const float*)d_in[14];
  const float* conv_nw = (const float*)d_in[15];
  const float* pw1_w   = (const float*)d_in[16];
  const float* pw1_b   = (const float*)d_in[17];
  const float* dw_w    = (const float*)d_in[18];
  const float* dw_b    = (const float*)d_in[19];
  const float* bn_g    = (const float*)d_in[20];
  const float* bn_b    = (const float*)d_in[21];
  const float* pw2_w   = (const float*)d_in[22];
  const float* pw2_b   = (const float*)d_in[23];
  const float* ff2_nw  = (const float*)d_in[24];
  const float* ff2_w1  = (const float*)d_in[25];
  const float* ff2_b1  = (const float*)d_in[26];
  const float* ff2_w2  = (const float*)d_in[27];
  const float* ff2_b2  = (const float*)d_in[28];
  const float* out_nw  = (const float*)d_in[29];

  float* out_x  = (float*)d_out;
  float* out_kv = out_x + (size_t)RR * DM;

  // ---- workspace layout ----
  u16* wt_ff1w1 = (u16*)d_ws;                          // 3072 x 768
  u16* wt_ff1w2 = wt_ff1w1 + (size_t)3072 * 768;       // 768 x 3072
  u16* wt_qkv   = wt_ff1w2 + (size_t)768 * 3072;       // 2304 x 768
  u16* wt_out   = wt_qkv   + (size_t)2304 * 768;       // 768 x 768
  u16* wt_pw1   = wt_out   + (size_t)768 * 768;        // 1536 x 768
  u16* wt_pw2   = wt_pw1   + (size_t)1536 * 768;       // 768 x 768
  u16* wt_ff2w1 = wt_pw2   + (size_t)768 * 768;        // 3072 x 768
  u16* wt_ff2w2 = wt_ff2w1 + (size_t)3072 * 768;       // 768 x 3072
  u16* abuf     = wt_ff2w2 + (size_t)768 * 3072;       // RR x 768 bf16
  u16* hbuf     = abuf + (size_t)RR * DM;              // RR x 3072 bf16
  float* xA     = (float*)(hbuf + (size_t)RR * FFD);   // RR x 768 f32
  float* xB     = xA + (size_t)RR * DM;                // RR x 768 f32
  float* qkvbuf = xB + (size_t)RR * DM;                // RR x 2304 f32
  u16* qbf      = (u16*)(qkvbuf + (size_t)RR * 3 * DM);
  u16* krotbf   = qbf + (size_t)RR * DM;
  u16* vtbf     = krotbf + (size_t)Bc * KVL * DM;
  float* bn_stats = (float*)(vtbf + (size_t)Bc * KVL * DM);
  // aliases (disjoint lifetimes):
  u16* attnout  = (u16*)qkvbuf;                        // RR x 768 bf16
  float* dwout  = qkvbuf;                              // RR x 768 f32 (conv phase)
  u16* bnout    = (u16*)(qkvbuf + (size_t)RR * DM);    // RR x 768 bf16 (conv phase)

  const dim3 blk(256);
  // ---- weight prep + stats zero: ONE launch ----
  k_wt_all<<<3318, blk, 0, stream>>>(ff1_w1, wt_ff1w1, ff1_w2, wt_ff1w2,
                                     qkv_w, wt_qkv, out_w, wt_out,
                                     pw1_w, wt_pw1, pw2_w, wt_pw2,
                                     ff2_w1, wt_ff2w1, ff2_w2, wt_ff2w2,
                                     bn_stats);

  // ---- FF1 ----
  k_rmsnorm2<true><<<RR, blk, 0, stream>>>(x, ff1_nw, abuf);
  k_gemm_mfma<128, 128, 32, 1, true><<<dim3(FFD / 128, RR / 128), blk, 0, stream>>>(
      abuf, wt_ff1w1, ff1_b1, nullptr, hbuf, DM, FFD);
  k_gemm_mfma<64, 64, 64, 2, false><<<dim3(DM / 64, RR / 64), blk, 0, stream>>>(
      hbuf, wt_ff1w2, ff1_b2, x, xA, FFD, DM);
  // ---- Attention ----
  k_rmsnorm2<true><<<RR, blk, 0, stream>>>(xA, attn_nw, abuf);
  k_gemm_mfma<128, 128, 32, 0, false><<<dim3(3 * DM / 128, RR / 128), blk, 0, stream>>>(
      abuf, wt_qkv, nullptr, nullptr, qkvbuf, DM, 3 * DM);
  k_qkvcache<<<RR + Bc * CACHE, 768, 0, stream>>>(qkvbuf, cached, q_nw, k_nw,
                                                  qbf, krotbf, out_kv);
  k_vt<<<Bc * NH * (KVL / 64), blk, 0, stream>>>(out_kv, vtbf);
  k_attn3<<<Bc * NH * (Nn / 64), blk, 0, stream>>>(qbf, krotbf, vtbf, attnout);
  k_gemm_mfma<64, 64, 64, 3, false><<<dim3(DM / 64, RR / 64), blk, 0, stream>>>(
      attnout, wt_out, nullptr, xA, xB, DM, DM);
  // ---- Conv module ----
  k_rmsnorm2<true><<<RR, blk, 0, stream>>>(xB, conv_nw, abuf);
  k_gemm_mfma<64, 128, 32, 0, true><<<dim3(2 * DM / 128, RR / 64), blk, 0, stream>>>(
      abuf, wt_pw1, pw1_b, nullptr, hbuf, DM, 2 * DM);
  k_dwconv2<<<dim3(DM / 64, Nn / 64, Bc), blk, 0, stream>>>(hbuf, dw_w, dw_b,
                                                            dwout, bn_stats);
  k_bn_apply<<<RR * DM / 256, blk, 0, stream>>>(dwout, bn_stats, bn_g, bn_b, bnout);
  k_gemm_mfma<64, 64, 64, 0, false><<<dim3(DM / 64, RR / 64), blk, 0, stream>>>(
      bnout, wt_pw2, pw2_b, nullptr, xA, DM, DM);
  // ---- FF2 ----
  k_rmsnorm2<true><<<RR, blk, 0, stream>>>(xA, ff2_nw, abuf);
  k_gemm_mfma<128, 128, 32, 1, true><<<dim3(FFD / 128, RR / 128), blk, 0, stream>>>(
      abuf, wt_ff2w1, ff2_b1, nullptr, hbuf, DM, FFD);
  k_gemm_mfma<64, 64, 64, 2, false><<<dim3(DM / 64, RR / 64), blk, 0, stream>>>(
      hbuf, wt_ff2w2, ff2_b2, xA, xB, FFD, DM);
  // ---- final norm ----
  k_rmsnorm2<false><<<RR, blk, 0, stream>>>(xB, out_nw, out_x);
}